// Round 6
// baseline (156.029 us; speedup 1.0000x reference)
//
#include <hip/hip_runtime.h>

// Problem constants
#define Bn  4
#define Cc  64      // channels
#define ICc 32      // inner channels
#define Hh  128
#define Ww  128
#define Nn  (Hh*Ww)     // 16384
#define Hp  (Hh/2)      // 64 pooled rows
#define Wp  (Ww/2)      // 64 pooled cols
#define Mm  (Hp*Wp)     // 4096 pooled positions
#define PAD 66          // LDS tile row stride (floats): 8B-aligned, breaks bank stride

// ---------------------------------------------------------------------------
// Kernel 0: zero the 16 KB gram accumulator (ws is poisoned 0xAA).
// 4 blocks x 256 threads x float4 = 4096 floats.
// ---------------------------------------------------------------------------
__global__ __launch_bounds__(256) void zero_A(float* __restrict__ A)
{
    ((float4*)A)[blockIdx.x * 256 + threadIdx.x] = make_float4(0.f, 0.f, 0.f, 0.f);
}

// ---------------------------------------------------------------------------
// Kernel 1: fused conv1x1 + 2x2 maxpool + partial gram.
// grid (Hp, B) = 256 blocks, block 256. Thread t: r = t&1 (row parity),
// img = (t>>1)&1 (0=phi/ref, 1=g/ref_align), pw = t>>2 (pooled col).
// Phase A: 32-IC conv at 2 horizontal px (float2), hmax, vmax via shfl pair
//          -> tile[img][ic][pw] in LDS (P/G never hit global memory).
// Phase B: partial A[i,j] = sum_pw g[i][pw]*phi[j][pw]; 4 entries/thread;
//          atomicAdd into global A (64 contributors per entry).
// ---------------------------------------------------------------------------
__global__ __launch_bounds__(256) void conv_gram_kernel(
    const float* __restrict__ ref, const float* __restrict__ ref_align,
    const float* __restrict__ phi_w, const float* __restrict__ phi_b,
    const float* __restrict__ g_w,   const float* __restrict__ g_b,
    float* __restrict__ A)
{
    __shared__ float swT[2][Cc * ICc];       // [img][c*32+ic] transposed weights
    __shared__ float sb[2][ICc];
    __shared__ float tile[2][ICc][PAD];      // [img][ic][pw], padded rows

    const int b = blockIdx.y, ph = blockIdx.x, tid = threadIdx.x;

    for (int idx = tid; idx < Cc * ICc; idx += 256) {
        const int c = idx >> 5, i = idx & 31;
        swT[0][idx] = phi_w[i * Cc + c];
        swT[1][idx] = g_w[i * Cc + c];
    }
    if (tid < ICc) { sb[0][tid] = phi_b[tid]; sb[1][tid] = g_b[tid]; }
    __syncthreads();

    const int r   = tid & 1;
    const int img = (tid >> 1) & 1;
    const int pw  = tid >> 2;
    const float* in = img ? ref_align : ref;
    // element addr = ((b*Cc + c)*Hh + hh)*Ww + px ; float2 units below
    const float2* xrow = (const float2*)in
                       + ((size_t)(b * Cc * Hh) + 2 * ph + r) * (Ww / 2);
    const int cs2 = (Hh * Ww) / 2;           // channel stride in float2
    const float* wimg = swT[img];

    float acc0[ICc], acc1[ICc];
    #pragma unroll
    for (int i = 0; i < ICc; ++i) { acc0[i] = sb[img][i]; acc1[i] = sb[img][i]; }

    #pragma unroll 4
    for (int c = 0; c < Cc; ++c) {
        const float2 v = xrow[c * cs2 + pw];
        const float4* w4 = (const float4*)(wimg + c * ICc);   // ds_read_b128 x8
        #pragma unroll
        for (int q = 0; q < 8; ++q) {
            const float4 w = w4[q];
            acc0[4*q+0] = fmaf(w.x, v.x, acc0[4*q+0]);
            acc1[4*q+0] = fmaf(w.x, v.y, acc1[4*q+0]);
            acc0[4*q+1] = fmaf(w.y, v.x, acc0[4*q+1]);
            acc1[4*q+1] = fmaf(w.y, v.y, acc1[4*q+1]);
            acc0[4*q+2] = fmaf(w.z, v.x, acc0[4*q+2]);
            acc1[4*q+2] = fmaf(w.z, v.y, acc1[4*q+2]);
            acc0[4*q+3] = fmaf(w.w, v.x, acc0[4*q+3]);
            acc1[4*q+3] = fmaf(w.w, v.y, acc1[4*q+3]);
        }
    }

    #pragma unroll
    for (int i = 0; i < ICc; ++i) {
        float mx = fmaxf(acc0[i], acc1[i]);              // horizontal max
        mx = fmaxf(mx, __shfl_xor(mx, 1, 64));           // vertical: pair lane
        if (r == 0) tile[img][i][pw] = mx;
    }
    __syncthreads();

    // Phase B: partial gram. thread -> (i = tid>>3, j0 = (tid&7)*4)
    const int i  = tid >> 3;
    const int j0 = (tid & 7) * 4;
    float s0 = 0.f, s1 = 0.f, s2 = 0.f, s3 = 0.f;
    #pragma unroll 8
    for (int p = 0; p < Wp / 2; ++p) {
        const float2 gv = *(const float2*)&tile[1][i][2 * p];
        const float2 p0 = *(const float2*)&tile[0][j0 + 0][2 * p];
        const float2 p1 = *(const float2*)&tile[0][j0 + 1][2 * p];
        const float2 p2 = *(const float2*)&tile[0][j0 + 2][2 * p];
        const float2 p3 = *(const float2*)&tile[0][j0 + 3][2 * p];
        s0 = fmaf(gv.x, p0.x, fmaf(gv.y, p0.y, s0));
        s1 = fmaf(gv.x, p1.x, fmaf(gv.y, p1.y, s1));
        s2 = fmaf(gv.x, p2.x, fmaf(gv.y, p2.y, s2));
        s3 = fmaf(gv.x, p3.x, fmaf(gv.y, p3.y, s3));
    }
    float* Ab = A + ((size_t)b * ICc + i) * ICc + j0;
    atomicAdd(Ab + 0, s0);
    atomicAdd(Ab + 1, s1);
    atomicAdd(Ab + 2, s2);
    atomicAdd(Ab + 3, s3);
}

// ---------------------------------------------------------------------------
// Kernel 2: fused combine + apply, o-split 8 (R5 structure, direct A read).
// Prologue builds 8 rows of M'[o,c] = (W_w @ (A/N) @ theta_w)[o,c] + (o==c)
// and v[o] = (W_w @ (A/N) @ theta_b)[o] + W_b[o].
// Main: out[b,o,n] = sum_c M'[o,c] x[b,c,n] + v[o].
// grid (Nn/512, B, 8) = 1024 blocks x 4 waves = 16 waves/CU.
// ---------------------------------------------------------------------------
__global__ __launch_bounds__(256) void apply_kernel(
    const float* __restrict__ x, const float* __restrict__ A,
    const float* __restrict__ theta_w, const float* __restrict__ theta_b,
    const float* __restrict__ W_w,     const float* __restrict__ W_b,
    float* __restrict__ out)
{
    const int b  = blockIdx.y;
    const int ob = blockIdx.z * 8;

    __shared__ float sA[ICc * ICc];
    __shared__ float sT[8 * ICc];
    __shared__ float sM[8 * Cc];
    __shared__ float sv[8];

    for (int idx = threadIdx.x; idx < ICc * ICc; idx += 256)
        sA[idx] = A[(size_t)b * ICc * ICc + idx];
    __syncthreads();

    {   // sT[ol][j], 8*32 = 256 = blockDim
        const int ol = threadIdx.x >> 5, j = threadIdx.x & 31;
        const float* wr = W_w + (ob + ol) * ICc;
        float t = 0.f;
        #pragma unroll
        for (int i = 0; i < ICc; ++i) t = fmaf(wr[i], sA[i * ICc + j], t);
        sT[ol * ICc + j] = t;
    }
    __syncthreads();

    const float invN = 1.f / (float)Nn;
    for (int idx = threadIdx.x; idx < 8 * Cc; idx += 256) {
        const int ol = idx >> 6, c = idx & 63;
        float s = 0.f;
        #pragma unroll
        for (int j = 0; j < ICc; ++j) s = fmaf(sT[ol * ICc + j], theta_w[j * Cc + c], s);
        sM[idx] = s * invN + ((ob + ol) == c ? 1.f : 0.f);
    }
    if (threadIdx.x < 8) {
        float v = 0.f;
        #pragma unroll
        for (int j = 0; j < ICc; ++j) v = fmaf(sT[threadIdx.x * ICc + j], theta_b[j], v);
        sv[threadIdx.x] = v * invN + W_b[ob + threadIdx.x];
    }
    __syncthreads();

    const int n2 = blockIdx.x * 256 + threadIdx.x;     // float2 index
    const float2* xb  = (const float2*)(x + (size_t)b * Cc * Nn);
    float2*       ob2 = (float2*)(out + (size_t)b * Cc * Nn);

    float ax[8], ay[8];
    #pragma unroll
    for (int i = 0; i < 8; ++i) { ax[i] = sv[i]; ay[i] = sv[i]; }

    #pragma unroll 8
    for (int c = 0; c < Cc; ++c) {
        float2 xv = xb[c * (Nn / 2) + n2];
        #pragma unroll
        for (int i = 0; i < 8; ++i) {
            float w = sM[i * Cc + c];          // wave-broadcast, conflict-free
            ax[i] = fmaf(w, xv.x, ax[i]);
            ay[i] = fmaf(w, xv.y, ay[i]);
        }
    }

    #pragma unroll
    for (int i = 0; i < 8; ++i) {
        float2 o2; o2.x = ax[i]; o2.y = ay[i];
        ob2[(ob + i) * (Nn / 2) + n2] = o2;
    }
}

// ---------------------------------------------------------------------------
extern "C" void kernel_launch(void* const* d_in, const int* in_sizes, int n_in,
                              void* d_out, int out_size, void* d_ws, size_t ws_size,
                              hipStream_t stream) {
    const float* target    = (const float*)d_in[0];
    const float* ref       = (const float*)d_in[1];
    const float* ref_align = (const float*)d_in[2];
    const float* theta_w   = (const float*)d_in[3];
    const float* theta_b   = (const float*)d_in[4];
    const float* phi_w     = (const float*)d_in[5];
    const float* phi_b     = (const float*)d_in[6];
    const float* g_w       = (const float*)d_in[7];
    const float* g_b       = (const float*)d_in[8];
    const float* W_w       = (const float*)d_in[9];
    const float* W_b       = (const float*)d_in[10];
    float* out = (float*)d_out;

    // workspace: A[B*IC*IC] = 16 KB gram accumulator
    float* A = (float*)d_ws;

    zero_A<<<4, 256, 0, stream>>>(A);
    conv_gram_kernel<<<dim3(Hp, Bn), 256, 0, stream>>>(ref, ref_align,
                                                       phi_w, phi_b, g_w, g_b, A);
    apply_kernel<<<dim3(Nn / 512, Bn, 8), 256, 0, stream>>>(target, A,
                                                            theta_w, theta_b,
                                                            W_w, W_b, out);
}

// Round 7
// 146.526 us; speedup vs baseline: 1.0649x; 1.0649x over previous
//
#include <hip/hip_runtime.h>

// Problem constants
#define Bn  4
#define Cc  64      // channels
#define ICc 32      // inner channels
#define Hh  128
#define Ww  128
#define Nn  (Hh*Ww)     // 16384
#define Hp  (Hh/2)      // 64 pooled rows
#define Wp  (Ww/2)      // 64 pooled cols
#define PAD 66          // LDS tile row stride (floats)

// ---------------------------------------------------------------------------
// Kernel 0: zero the 16 KB gram accumulator (ws is poisoned 0xAA).
// ---------------------------------------------------------------------------
__global__ __launch_bounds__(256) void zero_A(float* __restrict__ A)
{
    ((float4*)A)[blockIdx.x * 256 + threadIdx.x] = make_float4(0.f, 0.f, 0.f, 0.f);
}

// ---------------------------------------------------------------------------
// Kernel 1: fused conv1x1 + 2x2 maxpool + partial gram.
// grid (Hp, B) = 256 blocks, block 1024 (16 waves -> 4 waves/SIMD).
// tid = (icg<<8)|(pw<<4)... decomposition below: r = tid&1, img = (tid>>1)&1,
// pw = (tid>>2)&15 combined with icg? -> we use: low 6 bits = (pw4<<2|img<<1|r)
// per wave, icg = tid>>8 selects the 8-IC chunk; pw = ((tid>>2)&63).
// Phase A: each thread: 8 ICs x 2 horizontal px conv over 64 c, hmax, vmax
//          via shfl pair -> tile[img][ic][pw] in LDS. 16 accs -> NO SPILL.
// Phase B: 1024 threads = 32x32 (i,j); dot over 64 pw (float2); one
//          atomicAdd per thread into global A.
// ---------------------------------------------------------------------------
__global__ __launch_bounds__(1024) void conv_gram_kernel(
    const float* __restrict__ ref, const float* __restrict__ ref_align,
    const float* __restrict__ phi_w, const float* __restrict__ phi_b,
    const float* __restrict__ g_w,   const float* __restrict__ g_b,
    float* __restrict__ A)
{
    __shared__ float swT[2][Cc * ICc];       // [img][c*32+ic] transposed weights
    __shared__ float sb[2][ICc];
    __shared__ float tile[2][ICc][PAD];      // [img][ic][pw]

    const int b = blockIdx.y, ph = blockIdx.x, tid = threadIdx.x;

    for (int idx = tid; idx < Cc * ICc; idx += 1024) {
        const int c = idx >> 5, i = idx & 31;
        swT[0][idx] = phi_w[i * Cc + c];
        swT[1][idx] = g_w[i * Cc + c];
    }
    if (tid < ICc) { sb[0][tid] = phi_b[tid]; sb[1][tid] = g_b[tid]; }
    __syncthreads();

    // ---- Phase A: conv + pool for an 8-IC chunk ----
    {
        const int r   = tid & 1;
        const int img = (tid >> 1) & 1;
        const int pw  = (tid >> 2) & 63;     // pooled col 0..63
        const int icg = (tid >> 8) * 8;      // IC chunk base: 0,8,16,24
        const float* in = img ? ref_align : ref;
        const float2* xrow = (const float2*)in
                           + ((size_t)(b * Cc * Hh) + 2 * ph + r) * (Ww / 2);
        const int cs2 = (Hh * Ww) / 2;       // channel stride in float2
        const float* wimg = swT[img];

        float acc0[8], acc1[8];
        #pragma unroll
        for (int i = 0; i < 8; ++i) { acc0[i] = sb[img][icg + i]; acc1[i] = acc0[i]; }

        #pragma unroll 8
        for (int c = 0; c < Cc; ++c) {
            const float2 v = xrow[c * cs2 + pw];
            const float4* w4 = (const float4*)(wimg + c * ICc + icg);  // 2x b128
            #pragma unroll
            for (int q = 0; q < 2; ++q) {
                const float4 w = w4[q];
                acc0[4*q+0] = fmaf(w.x, v.x, acc0[4*q+0]);
                acc1[4*q+0] = fmaf(w.x, v.y, acc1[4*q+0]);
                acc0[4*q+1] = fmaf(w.y, v.x, acc0[4*q+1]);
                acc1[4*q+1] = fmaf(w.y, v.y, acc1[4*q+1]);
                acc0[4*q+2] = fmaf(w.z, v.x, acc0[4*q+2]);
                acc1[4*q+2] = fmaf(w.z, v.y, acc1[4*q+2]);
                acc0[4*q+3] = fmaf(w.w, v.x, acc0[4*q+3]);
                acc1[4*q+3] = fmaf(w.w, v.y, acc1[4*q+3]);
            }
        }

        #pragma unroll
        for (int i = 0; i < 8; ++i) {
            float mx = fmaxf(acc0[i], acc1[i]);          // horizontal max
            mx = fmaxf(mx, __shfl_xor(mx, 1, 64));       // vertical: pair lane
            if (r == 0) tile[img][icg + i][pw] = mx;
        }
    }
    __syncthreads();

    // ---- Phase B: partial gram, one (i,j) per thread ----
    {
        const int i = tid >> 5;              // 0..31 (wave-uniform per half-wave)
        const int j = tid & 31;              // 0..31 across lanes
        float s = 0.f;
        #pragma unroll 8
        for (int p = 0; p < Wp / 2; ++p) {
            const float2 gv = *(const float2*)&tile[1][i][2 * p];  // broadcast
            const float2 pv = *(const float2*)&tile[0][j][2 * p];  // 2-way alias
            s = fmaf(gv.x, pv.x, fmaf(gv.y, pv.y, s));
        }
        atomicAdd(A + ((size_t)b * ICc + i) * ICc + j, s);
    }
}

// ---------------------------------------------------------------------------
// Kernel 2: fused combine + apply, o-split 8 (R5 structure, direct A read).
// Prologue builds 8 rows of M'[o,c] = (W_w @ (A/N) @ theta_w)[o,c] + (o==c)
// and v[o] = (W_w @ (A/N) @ theta_b)[o] + W_b[o].
// Main: out[b,o,n] = sum_c M'[o,c] x[b,c,n] + v[o].
// grid (Nn/512, B, 8) = 1024 blocks x 4 waves = 16 waves/CU.
// ---------------------------------------------------------------------------
__global__ __launch_bounds__(256) void apply_kernel(
    const float* __restrict__ x, const float* __restrict__ A,
    const float* __restrict__ theta_w, const float* __restrict__ theta_b,
    const float* __restrict__ W_w,     const float* __restrict__ W_b,
    float* __restrict__ out)
{
    const int b  = blockIdx.y;
    const int ob = blockIdx.z * 8;

    __shared__ float sA[ICc * ICc];
    __shared__ float sT[8 * ICc];
    __shared__ float sM[8 * Cc];
    __shared__ float sv[8];

    for (int idx = threadIdx.x; idx < ICc * ICc; idx += 256)
        sA[idx] = A[(size_t)b * ICc * ICc + idx];
    __syncthreads();

    {   // sT[ol][j], 8*32 = 256 = blockDim
        const int ol = threadIdx.x >> 5, j = threadIdx.x & 31;
        const float* wr = W_w + (ob + ol) * ICc;
        float t = 0.f;
        #pragma unroll
        for (int i = 0; i < ICc; ++i) t = fmaf(wr[i], sA[i * ICc + j], t);
        sT[ol * ICc + j] = t;
    }
    __syncthreads();

    const float invN = 1.f / (float)Nn;
    for (int idx = threadIdx.x; idx < 8 * Cc; idx += 256) {
        const int ol = idx >> 6, c = idx & 63;
        float s = 0.f;
        #pragma unroll
        for (int j = 0; j < ICc; ++j) s = fmaf(sT[ol * ICc + j], theta_w[j * Cc + c], s);
        sM[idx] = s * invN + ((ob + ol) == c ? 1.f : 0.f);
    }
    if (threadIdx.x < 8) {
        float v = 0.f;
        #pragma unroll
        for (int j = 0; j < ICc; ++j) v = fmaf(sT[threadIdx.x * ICc + j], theta_b[j], v);
        sv[threadIdx.x] = v * invN + W_b[ob + threadIdx.x];
    }
    __syncthreads();

    const int n2 = blockIdx.x * 256 + threadIdx.x;     // float2 index
    const float2* xb  = (const float2*)(x + (size_t)b * Cc * Nn);
    float2*       ob2 = (float2*)(out + (size_t)b * Cc * Nn);

    float ax[8], ay[8];
    #pragma unroll
    for (int i = 0; i < 8; ++i) { ax[i] = sv[i]; ay[i] = sv[i]; }

    #pragma unroll 8
    for (int c = 0; c < Cc; ++c) {
        float2 xv = xb[c * (Nn / 2) + n2];
        #pragma unroll
        for (int i = 0; i < 8; ++i) {
            float w = sM[i * Cc + c];          // wave-broadcast, conflict-free
            ax[i] = fmaf(w, xv.x, ax[i]);
            ay[i] = fmaf(w, xv.y, ay[i]);
        }
    }

    #pragma unroll
    for (int i = 0; i < 8; ++i) {
        float2 o2; o2.x = ax[i]; o2.y = ay[i];
        ob2[(ob + i) * (Nn / 2) + n2] = o2;
    }
}

// ---------------------------------------------------------------------------
extern "C" void kernel_launch(void* const* d_in, const int* in_sizes, int n_in,
                              void* d_out, int out_size, void* d_ws, size_t ws_size,
                              hipStream_t stream) {
    const float* target    = (const float*)d_in[0];
    const float* ref       = (const float*)d_in[1];
    const float* ref_align = (const float*)d_in[2];
    const float* theta_w   = (const float*)d_in[3];
    const float* theta_b   = (const float*)d_in[4];
    const float* phi_w     = (const float*)d_in[5];
    const float* phi_b     = (const float*)d_in[6];
    const float* g_w       = (const float*)d_in[7];
    const float* g_b       = (const float*)d_in[8];
    const float* W_w       = (const float*)d_in[9];
    const float* W_b       = (const float*)d_in[10];
    float* out = (float*)d_out;

    // workspace: A[B*IC*IC] = 16 KB gram accumulator
    float* A = (float*)d_ws;

    zero_A<<<4, 256, 0, stream>>>(A);
    conv_gram_kernel<<<dim3(Hp, Bn), 1024, 0, stream>>>(ref, ref_align,
                                                        phi_w, phi_b, g_w, g_b, A);
    apply_kernel<<<dim3(Nn / 512, Bn, 8), 256, 0, stream>>>(target, A,
                                                            theta_w, theta_b,
                                                            W_w, W_b, out);
}